// Round 1
// baseline (267.736 us; speedup 1.0000x reference)
//
#include <hip/hip_runtime.h>
#include <hip/hip_bf16.h>
#include <math.h>

#define B_   32
#define CI   256
#define CO   256
#define KW   7
#define NW   8
#define SQD  8
#define L_   4096

typedef __attribute__((ext_vector_type(8))) __bf16 bf16x8;
typedef __attribute__((ext_vector_type(4))) float  f32x4;

static __device__ __forceinline__ unsigned short f2bf(float f) {
    unsigned int u = __builtin_bit_cast(unsigned int, f);
    u += 0x7FFFu + ((u >> 16) & 1u);
    return (unsigned short)(u >> 16);
}

// ---------------------------------------------------------------------------
// k1: mean over L (partial sums via atomicAdd) + transpose x[b][i][l] ->
//     xT[b][l][i] as bf16.  Tile: 64 i x 128 l per block, 256 threads.
// ---------------------------------------------------------------------------
__global__ __launch_bounds__(256) void k1_mean_transpose(
        const float* __restrict__ x,
        unsigned short* __restrict__ xT,     // bf16 bits [B][L][CI]
        float* __restrict__ pooled) {        // [B][CI]  (sums; /L later)
    int b  = blockIdx.z;
    int i0 = blockIdx.y * 64;
    int l0 = blockIdx.x * 128;
    __shared__ float tile[64][129];          // +1 pad: column reads ~conflict-free
    int t  = threadIdx.x;
    int lv = (t & 31) * 4;                   // float4 column offset within tile
    int ib = t >> 5;                         // row group 0..7

    const float* xb = x + (size_t)b * CI * L_;
    for (int it = 0; it < 8; ++it) {
        int i = ib + 8 * it;                 // local row 0..63
        float4 v = *(const float4*)(xb + (size_t)(i0 + i) * L_ + l0 + lv);
        tile[i][lv + 0] = v.x;
        tile[i][lv + 1] = v.y;
        tile[i][lv + 2] = v.z;
        tile[i][lv + 3] = v.w;
        float ps = v.x + v.y + v.z + v.w;
        // reduce across the 32 lanes sharing this row
        for (int m = 1; m <= 16; m <<= 1) ps += __shfl_xor(ps, m);
        if ((t & 31) == 0) atomicAdd(pooled + b * CI + i0 + i, ps);
    }
    __syncthreads();
    // write out transposed rows: xT[b][l0+l][i0 .. i0+63]
    for (int u = t; u < 128 * 8; u += 256) {
        int l = u >> 3, ig = u & 7;          // ig: 8-element i group
        unsigned int pk[4];
#pragma unroll
        for (int q = 0; q < 4; ++q) {
            float a = tile[ig * 8 + 2 * q + 0][l];
            float c = tile[ig * 8 + 2 * q + 1][l];
            pk[q] = (unsigned int)f2bf(a) | ((unsigned int)f2bf(c) << 16);
        }
        uint4 w4; w4.x = pk[0]; w4.y = pk[1]; w4.z = pk[2]; w4.w = pk[3];
        *(uint4*)(xT + ((size_t)b * L_ + l0 + l) * CI + i0 + ig * 8) = w4;
    }
}

// ---------------------------------------------------------------------------
// k2: squeeze net + gates. one block (64 threads = 1 wave) per sample.
// ---------------------------------------------------------------------------
__global__ __launch_bounds__(64) void k2_gates(
        const float* __restrict__ pooled,
        const float* __restrict__ w1, const float* __restrict__ b1,
        const float* __restrict__ wk, const float* __restrict__ wi,
        const float* __restrict__ wo, const float* __restrict__ wn,
        float* __restrict__ kr,   // [B][8] (stride 8, 7 used)
        float* __restrict__ inc,  // [B][CI]
        float* __restrict__ outc, // [B][CO]
        float* __restrict__ nums) // [B][NW]
{
    int b = blockIdx.x, lane = threadIdx.x;
    float pc[4];
#pragma unroll
    for (int j = 0; j < 4; ++j)
        pc[j] = pooled[b * CI + lane + 64 * j] * (1.0f / L_);
    float h[SQD];
#pragma unroll
    for (int s = 0; s < SQD; ++s) {
        float ps = 0.f;
#pragma unroll
        for (int j = 0; j < 4; ++j)
            ps += pc[j] * w1[(lane + 64 * j) * SQD + s];
        for (int m = 1; m <= 32; m <<= 1) ps += __shfl_xor(ps, m);
        float z = ps + b1[s];
        h[s] = 0.5f * z * (1.0f + erff(z * 0.70710678118654752f)); // exact GELU
    }
    if (lane < KW) {
        float a = 0.f;
#pragma unroll
        for (int s = 0; s < SQD; ++s) a += h[s] * wk[s * KW + lane];
        kr[b * 8 + lane] = 1.0f / (1.0f + expf(-a));
    }
    if (lane < NW) {
        float e[NW]; float mx = -1e30f;
#pragma unroll
        for (int n = 0; n < NW; ++n) {
            float a = 0.f;
#pragma unroll
            for (int s = 0; s < SQD; ++s) a += h[s] * wn[s * NW + n];
            e[n] = a; mx = fmaxf(mx, a);
        }
        float den = 0.f;
#pragma unroll
        for (int n = 0; n < NW; ++n) den += expf(e[n] - mx);
        nums[b * NW + lane] = expf(e[lane] - mx) / den;
    }
#pragma unroll
    for (int j = 0; j < 4; ++j) {
        int c = lane + 64 * j;
        float a = 0.f, o2 = 0.f;
#pragma unroll
        for (int s = 0; s < SQD; ++s) {
            a  += h[s] * wi[s * CI + c];
            o2 += h[s] * wo[s * CO + c];
        }
        inc[b * CI + c]  = 1.0f / (1.0f + expf(-a));
        outc[b * CO + c] = 1.0f / (1.0f + expf(-o2));
    }
}

// ---------------------------------------------------------------------------
// k3: per-sample mixed weights in MFMA-native layout
//     W2[b][k][i/32][o][i%32] (bf16).  256 blocks x 256 threads.
//     block: ic = bx&7, o0 = (bx>>3)*8;  thread: ii = t&31, oo = t>>5.
// ---------------------------------------------------------------------------
__global__ __launch_bounds__(256) void k3_wgen(
        const float* __restrict__ cw,      // [CO][CI][KW][NW]
        const float* __restrict__ kr, const float* __restrict__ inc,
        const float* __restrict__ outc, const float* __restrict__ nums,
        unsigned short* __restrict__ W2) {
    __shared__ float s_nums[B_][NW];
    __shared__ float s_kr[B_][KW];
    __shared__ float s_inc[B_][32];
    __shared__ float s_outc[B_][8];
    int t = threadIdx.x;
    int ic = blockIdx.x & 7, o0 = (blockIdx.x >> 3) * 8;
    s_nums[t >> 3][t & 7] = nums[t];                       // 256 values
    if (t < B_ * KW) s_kr[t / KW][t % KW] = kr[(t / KW) * 8 + (t % KW)];
    for (int u = t; u < 32 * 32; u += 256) {
        int bb = u >> 5, ii = u & 31;
        s_inc[bb][ii] = inc[bb * CI + ic * 32 + ii];
    }
    for (int u = t; u < 32 * 8; u += 256) {
        int bb = u >> 3, oo = u & 7;
        s_outc[bb][oo] = outc[bb * CO + o0 + oo];
    }
    __syncthreads();
    int ii = t & 31, oo = t >> 5;
    int o = o0 + oo, i = ic * 32 + ii;
    float cwv[KW][NW];
    const float* p = cw + ((size_t)(o * CI + i)) * (KW * NW);
#pragma unroll
    for (int k = 0; k < KW; ++k)
#pragma unroll
        for (int n = 0; n < NW; ++n) cwv[k][n] = p[k * NW + n];
    for (int bb = 0; bb < B_; ++bb) {
        float gio = s_inc[bb][ii] * s_outc[bb][oo];
#pragma unroll
        for (int k = 0; k < KW; ++k) {
            float sk = 0.f;
#pragma unroll
            for (int n = 0; n < NW; ++n) sk += s_nums[bb][n] * cwv[k][n];
            float w = s_kr[bb][k] * gio * sk;
            W2[(((size_t)(bb * KW + k) * 8 + ic) * CO + o) * 32 + ii] = f2bf(w);
        }
    }
}

// ---------------------------------------------------------------------------
// k4: the conv as per-sample im2col GEMM with 16x16x32 bf16 MFMA.
//     Block = 128 o x 128 l for one sample; 4 waves in 2x2; acc[4][4].
//     x tile staged once to LDS transposed [134][264] bf16 (pitch 264:
//     row stride 528 B = 132 dw = +4 banks/row -> ~conflict-free b128 reads).
// ---------------------------------------------------------------------------
__global__ __launch_bounds__(256) void k4_conv(
        const unsigned short* __restrict__ xT,   // bf16 [B][L][CI]
        const unsigned short* __restrict__ W2,   // bf16 [B][KW][8][CO][32]
        float* __restrict__ out) {               // [B][CO][L]
    constexpr int PITCH = 264;
    __shared__ __align__(16) unsigned short xs[134 * PITCH];
    int b = blockIdx.z, o_blk = blockIdx.y * 128, l0 = blockIdx.x * 128;
    int t = threadIdx.x;

    // stage x rows l0-3 .. l0+130 (zero-padded at edges)
    for (int u = t; u < 134 * 32; u += 256) {
        int r = u >> 5, c = u & 31;              // c: 16B unit within 512B row
        int gl = l0 - 3 + r;
        uint4 v = make_uint4(0u, 0u, 0u, 0u);
        if (gl >= 0 && gl < L_)
            v = *(const uint4*)(xT + ((size_t)b * L_ + gl) * CI + c * 8);
        *(uint4*)(xs + r * PITCH + c * 8) = v;
    }
    __syncthreads();

    int lane = t & 63, wid = t >> 6;
    int wm = (wid >> 1) * 64, wn = (wid & 1) * 64;   // wave origin in tile
    int ml = lane & 15, kg = lane >> 4;

    f32x4 acc[4][4];
#pragma unroll
    for (int a = 0; a < 4; ++a)
#pragma unroll
        for (int c = 0; c < 4; ++c) acc[a][c] = (f32x4){0.f, 0.f, 0.f, 0.f};

    const unsigned short* wbase = W2 + (size_t)b * KW * 8 * CO * 32;
    for (int k = 0; k < KW; ++k) {
#pragma unroll
        for (int icc = 0; icc < 8; ++icc) {
            const unsigned short* wkc = wbase + (size_t)(k * 8 + icc) * (CO * 32);
            bf16x8 af[4], bfr[4];
#pragma unroll
            for (int mt = 0; mt < 4; ++mt) {
                int o = o_blk + wm + mt * 16 + ml;
                af[mt] = *(const bf16x8*)(wkc + o * 32 + kg * 8);
            }
#pragma unroll
            for (int nt = 0; nt < 4; ++nt) {
                int row = wn + nt * 16 + ml + k;
                bfr[nt] = *(const bf16x8*)(xs + row * PITCH + icc * 32 + kg * 8);
            }
#pragma unroll
            for (int mt = 0; mt < 4; ++mt)
#pragma unroll
                for (int nt = 0; nt < 4; ++nt)
                    acc[mt][nt] = __builtin_amdgcn_mfma_f32_16x16x32_bf16(
                        af[mt], bfr[nt], acc[mt][nt], 0, 0, 0);
        }
    }

    // epilogue: D row=(lane>>4)*4+q (o), col=lane&15 (l)
#pragma unroll
    for (int mt = 0; mt < 4; ++mt)
#pragma unroll
        for (int nt = 0; nt < 4; ++nt) {
            int o = o_blk + wm + mt * 16 + kg * 4;
            int l = l0 + wn + nt * 16 + ml;
#pragma unroll
            for (int q = 0; q < 4; ++q)
                out[((size_t)(b * CO + o + q)) * L_ + l] = acc[mt][nt][q];
        }
}

// ---------------------------------------------------------------------------
extern "C" void kernel_launch(void* const* d_in, const int* in_sizes, int n_in,
                              void* d_out, int out_size, void* d_ws, size_t ws_size,
                              hipStream_t stream) {
    const float* x  = (const float*)d_in[0];
    const float* cw = (const float*)d_in[1];
    const float* w1 = (const float*)d_in[2];
    const float* b1 = (const float*)d_in[3];
    const float* wk = (const float*)d_in[4];
    const float* wi = (const float*)d_in[5];
    const float* wo = (const float*)d_in[6];
    const float* wn = (const float*)d_in[7];
    float* out = (float*)d_out;

    char* ws = (char*)d_ws;
    const size_t off_xT     = 0;                       // 32*4096*256*2 = 67108864
    const size_t off_W2     = 67108864;                // 32*7*8*256*32*2 = 29360128
    const size_t off_pooled = 96468992;                // 32*256*4 = 32768
    const size_t off_kr     = 96501760;                // 32*8*4 = 1024
    const size_t off_inc    = 96502784;                // 32768
    const size_t off_outc   = 96535552;                // 32768
    const size_t off_nums   = 96568320;                // 1024

    unsigned short* xT  = (unsigned short*)(ws + off_xT);
    unsigned short* W2  = (unsigned short*)(ws + off_W2);
    float* pooled = (float*)(ws + off_pooled);
    float* kr     = (float*)(ws + off_kr);
    float* inc    = (float*)(ws + off_inc);
    float* outc   = (float*)(ws + off_outc);
    float* nums   = (float*)(ws + off_nums);

    hipMemsetAsync(pooled, 0, B_ * CI * sizeof(float), stream);
    k1_mean_transpose<<<dim3(32, 4, B_), 256, 0, stream>>>(x, xT, pooled);
    k2_gates<<<B_, 64, 0, stream>>>(pooled, w1, b1, wk, wi, wo, wn,
                                    kr, inc, outc, nums);
    k3_wgen<<<256, 256, 0, stream>>>(cw, kr, inc, outc, nums, W2);
    k4_conv<<<dim3(32, 2, B_), 256, 0, stream>>>(xT, W2, out);
}

// Round 2
// 201.437 us; speedup vs baseline: 1.3291x; 1.3291x over previous
//
#include <hip/hip_runtime.h>
#include <hip/hip_bf16.h>
#include <math.h>

#define B_   32
#define CI   256
#define CO   256
#define KW   7
#define NW   8
#define SQD  8
#define L_   4096

typedef __attribute__((ext_vector_type(8))) __bf16 bf16x8;
typedef __attribute__((ext_vector_type(4))) float  f32x4;

static __device__ __forceinline__ unsigned short f2bf(float f) {
    unsigned int u = __builtin_bit_cast(unsigned int, f);
    u += 0x7FFFu + ((u >> 16) & 1u);
    return (unsigned short)(u >> 16);
}

// ---------------------------------------------------------------------------
// k1: mean over L (partial sums via atomicAdd) + transpose x[b][i][l] ->
//     xT[b][l][i] as bf16.  Tile: 64 i x 128 l per block, 256 threads.
// ---------------------------------------------------------------------------
__global__ __launch_bounds__(256) void k1_mean_transpose(
        const float* __restrict__ x,
        unsigned short* __restrict__ xT,     // bf16 bits [B][L][CI]
        float* __restrict__ pooled) {        // [B][CI]  (sums; /L later)
    int b  = blockIdx.z;
    int i0 = blockIdx.y * 64;
    int l0 = blockIdx.x * 128;
    __shared__ float tile[64][129];
    int t  = threadIdx.x;
    int lv = (t & 31) * 4;
    int ib = t >> 5;

    const float* xb = x + (size_t)b * CI * L_;
    for (int it = 0; it < 8; ++it) {
        int i = ib + 8 * it;
        float4 v = *(const float4*)(xb + (size_t)(i0 + i) * L_ + l0 + lv);
        tile[i][lv + 0] = v.x;
        tile[i][lv + 1] = v.y;
        tile[i][lv + 2] = v.z;
        tile[i][lv + 3] = v.w;
        float ps = v.x + v.y + v.z + v.w;
        for (int m = 1; m <= 16; m <<= 1) ps += __shfl_xor(ps, m);
        if ((t & 31) == 0) atomicAdd(pooled + b * CI + i0 + i, ps);
    }
    __syncthreads();
    for (int u = t; u < 128 * 8; u += 256) {
        int l = u >> 3, ig = u & 7;
        unsigned int pk[4];
#pragma unroll
        for (int q = 0; q < 4; ++q) {
            float a = tile[ig * 8 + 2 * q + 0][l];
            float c = tile[ig * 8 + 2 * q + 1][l];
            pk[q] = (unsigned int)f2bf(a) | ((unsigned int)f2bf(c) << 16);
        }
        uint4 w4; w4.x = pk[0]; w4.y = pk[1]; w4.z = pk[2]; w4.w = pk[3];
        *(uint4*)(xT + ((size_t)b * L_ + l0 + l) * CI + i0 + ig * 8) = w4;
    }
}

// ---------------------------------------------------------------------------
// k2: squeeze net + gates. one block (64 threads = 1 wave) per sample.
// ---------------------------------------------------------------------------
__global__ __launch_bounds__(64) void k2_gates(
        const float* __restrict__ pooled,
        const float* __restrict__ w1, const float* __restrict__ b1,
        const float* __restrict__ wk, const float* __restrict__ wi,
        const float* __restrict__ wo, const float* __restrict__ wn,
        float* __restrict__ kr,   // [B][8] (stride 8, 7 used)
        float* __restrict__ inc,  // [B][CI]
        float* __restrict__ outc, // [B][CO]
        float* __restrict__ nums) // [B][NW]
{
    int b = blockIdx.x, lane = threadIdx.x;
    float pc[4];
#pragma unroll
    for (int j = 0; j < 4; ++j)
        pc[j] = pooled[b * CI + lane + 64 * j] * (1.0f / L_);
    float h[SQD];
#pragma unroll
    for (int s = 0; s < SQD; ++s) {
        float ps = 0.f;
#pragma unroll
        for (int j = 0; j < 4; ++j)
            ps += pc[j] * w1[(lane + 64 * j) * SQD + s];
        for (int m = 1; m <= 32; m <<= 1) ps += __shfl_xor(ps, m);
        float z = ps + b1[s];
        h[s] = 0.5f * z * (1.0f + erff(z * 0.70710678118654752f));
    }
    if (lane < KW) {
        float a = 0.f;
#pragma unroll
        for (int s = 0; s < SQD; ++s) a += h[s] * wk[s * KW + lane];
        kr[b * 8 + lane] = 1.0f / (1.0f + expf(-a));
    }
    if (lane < NW) {
        float e[NW]; float mx = -1e30f;
#pragma unroll
        for (int n = 0; n < NW; ++n) {
            float a = 0.f;
#pragma unroll
            for (int s = 0; s < SQD; ++s) a += h[s] * wn[s * NW + n];
            e[n] = a; mx = fmaxf(mx, a);
        }
        float den = 0.f;
#pragma unroll
        for (int n = 0; n < NW; ++n) den += expf(e[n] - mx);
        nums[b * NW + lane] = expf(e[lane] - mx) / den;
    }
#pragma unroll
    for (int j = 0; j < 4; ++j) {
        int c = lane + 64 * j;
        float a = 0.f, o2 = 0.f;
#pragma unroll
        for (int s = 0; s < SQD; ++s) {
            a  += h[s] * wi[s * CI + c];
            o2 += h[s] * wo[s * CO + c];
        }
        inc[b * CI + c]  = 1.0f / (1.0f + expf(-a));
        outc[b * CO + c] = 1.0f / (1.0f + expf(-o2));
    }
}

// ---------------------------------------------------------------------------
// k3: per-sample mixed weights in MFMA-native layout
//     W2[b][k][i/32][o][i%32] (bf16).  256 blocks x 256 threads.
// ---------------------------------------------------------------------------
__global__ __launch_bounds__(256) void k3_wgen(
        const float* __restrict__ cw,      // [CO][CI][KW][NW]
        const float* __restrict__ kr, const float* __restrict__ inc,
        const float* __restrict__ outc, const float* __restrict__ nums,
        unsigned short* __restrict__ W2) {
    __shared__ float s_nums[B_][NW];
    __shared__ float s_kr[B_][KW];
    __shared__ float s_inc[B_][32];
    __shared__ float s_outc[B_][8];
    int t = threadIdx.x;
    int ic = blockIdx.x & 7, o0 = (blockIdx.x >> 3) * 8;
    s_nums[t >> 3][t & 7] = nums[t];
    if (t < B_ * KW) s_kr[t / KW][t % KW] = kr[(t / KW) * 8 + (t % KW)];
    for (int u = t; u < 32 * 32; u += 256) {
        int bb = u >> 5, ii = u & 31;
        s_inc[bb][ii] = inc[bb * CI + ic * 32 + ii];
    }
    for (int u = t; u < 32 * 8; u += 256) {
        int bb = u >> 3, oo = u & 7;
        s_outc[bb][oo] = outc[bb * CO + o0 + oo];
    }
    __syncthreads();
    int ii = t & 31, oo = t >> 5;
    int o = o0 + oo, i = ic * 32 + ii;
    float cwv[KW][NW];
    const float* p = cw + ((size_t)(o * CI + i)) * (KW * NW);
#pragma unroll
    for (int k = 0; k < KW; ++k)
#pragma unroll
        for (int n = 0; n < NW; ++n) cwv[k][n] = p[k * NW + n];
    for (int bb = 0; bb < B_; ++bb) {
        float gio = s_inc[bb][ii] * s_outc[bb][oo];
#pragma unroll
        for (int k = 0; k < KW; ++k) {
            float sk = 0.f;
#pragma unroll
            for (int n = 0; n < NW; ++n) sk += s_nums[bb][n] * cwv[k][n];
            float w = s_kr[bb][k] * gio * sk;
            W2[(((size_t)(bb * KW + k) * 8 + ic) * CO + o) * 32 + ii] = f2bf(w);
        }
    }
}

// ---------------------------------------------------------------------------
// k4: per-sample im2col GEMM, 16x16x32 bf16 MFMA.
//     Block = 256 o x 256 l for one sample; 8 waves (4 o x 2 l),
//     wave tile = 64 o x 128 l, acc[4][8].
//     x tile staged ONCE: rows l0-3 .. l0+258 (262 rows x 256 bf16),
//     XOR-swizzled 16B units: unit c of row r stored at c^(r&7)
//     -> conflict-free ds_write_b128 and ds_read_b128.
// ---------------------------------------------------------------------------
__global__ __launch_bounds__(512, 2) void k4_conv(
        const unsigned short* __restrict__ xT,   // bf16 [B][L][CI]
        const unsigned short* __restrict__ W2,   // bf16 [B][KW][8][CO][32]
        float* __restrict__ out) {               // [B][CO][L]
    __shared__ __align__(16) unsigned short xs[262 * 256];
    int b = blockIdx.y, l0 = blockIdx.x * 256;
    int t = threadIdx.x;

    // stage rows l0-3 .. l0+258, swizzled (zero-pad edges)
    for (int u = t; u < 262 * 32; u += 512) {
        int r = u >> 5, c = u & 31;
        int gl = l0 - 3 + r;
        uint4 v = make_uint4(0u, 0u, 0u, 0u);
        if (gl >= 0 && gl < L_)
            v = *(const uint4*)(xT + ((size_t)b * L_ + gl) * CI + c * 8);
        *(uint4*)(xs + r * 256 + (c ^ (r & 7)) * 8) = v;
    }
    __syncthreads();

    int lane = t & 63, wid = t >> 6;
    int o_base = (wid & 3) * 64;          // wave o-range: 64
    int l_off  = (wid >> 2) * 128;        // wave l-range: 128
    int ml = lane & 15, kg = lane >> 4;

    f32x4 acc[4][8];
#pragma unroll
    for (int a = 0; a < 4; ++a)
#pragma unroll
        for (int c = 0; c < 8; ++c) acc[a][c] = (f32x4){0.f, 0.f, 0.f, 0.f};

    const unsigned short* wbase = W2 + (size_t)b * (KW * 8 * CO * 32);
    for (int k = 0; k < KW; ++k) {
        const unsigned short* wk_ = wbase + (size_t)k * (8 * CO * 32);
#pragma unroll
        for (int icc = 0; icc < 8; ++icc) {
            const unsigned short* wkc = wk_ + icc * (CO * 32);
            bf16x8 af[4];
#pragma unroll
            for (int mt = 0; mt < 4; ++mt)
                af[mt] = *(const bf16x8*)(wkc + (o_base + mt * 16 + ml) * 32 + kg * 8);
            bf16x8 bfr[8];
#pragma unroll
            for (int nt = 0; nt < 8; ++nt) {
                int r = l_off + nt * 16 + ml + k;
                int unit = (icc * 4 + kg) ^ (r & 7);
                bfr[nt] = *(const bf16x8*)(xs + r * 256 + unit * 8);
            }
#pragma unroll
            for (int mt = 0; mt < 4; ++mt)
#pragma unroll
                for (int nt = 0; nt < 8; ++nt)
                    acc[mt][nt] = __builtin_amdgcn_mfma_f32_16x16x32_bf16(
                        af[mt], bfr[nt], acc[mt][nt], 0, 0, 0);
        }
    }

    // epilogue: D row(o)=(lane>>4)*4+q, col(l)=lane&15
#pragma unroll
    for (int mt = 0; mt < 4; ++mt) {
        int o = o_base + mt * 16 + kg * 4;
#pragma unroll
        for (int nt = 0; nt < 8; ++nt) {
            int l = l0 + l_off + nt * 16 + ml;
            float* po = out + ((size_t)(b * CO + o)) * L_ + l;
#pragma unroll
            for (int q = 0; q < 4; ++q)
                po[(size_t)q * L_] = acc[mt][nt][q];
        }
    }
}

// ---------------------------------------------------------------------------
extern "C" void kernel_launch(void* const* d_in, const int* in_sizes, int n_in,
                              void* d_out, int out_size, void* d_ws, size_t ws_size,
                              hipStream_t stream) {
    const float* x  = (const float*)d_in[0];
    const float* cw = (const float*)d_in[1];
    const float* w1 = (const float*)d_in[2];
    const float* b1 = (const float*)d_in[3];
    const float* wk = (const float*)d_in[4];
    const float* wi = (const float*)d_in[5];
    const float* wo = (const float*)d_in[6];
    const float* wn = (const float*)d_in[7];
    float* out = (float*)d_out;

    char* ws = (char*)d_ws;
    const size_t off_xT     = 0;                       // 32*4096*256*2
    const size_t off_W2     = 67108864;                // 32*7*8*256*32*2
    const size_t off_pooled = 96468992;
    const size_t off_kr     = 96501760;
    const size_t off_inc    = 96502784;
    const size_t off_outc   = 96535552;
    const size_t off_nums   = 96568320;

    unsigned short* xT  = (unsigned short*)(ws + off_xT);
    unsigned short* W2  = (unsigned short*)(ws + off_W2);
    float* pooled = (float*)(ws + off_pooled);
    float* kr     = (float*)(ws + off_kr);
    float* inc    = (float*)(ws + off_inc);
    float* outc   = (float*)(ws + off_outc);
    float* nums   = (float*)(ws + off_nums);

    hipMemsetAsync(pooled, 0, B_ * CI * sizeof(float), stream);
    k1_mean_transpose<<<dim3(32, 4, B_), 256, 0, stream>>>(x, xT, pooled);
    k2_gates<<<B_, 64, 0, stream>>>(pooled, w1, b1, wk, wi, wo, wn,
                                    kr, inc, outc, nums);
    k3_wgen<<<256, 256, 0, stream>>>(cw, kr, inc, outc, nums, W2);
    k4_conv<<<dim3(16, 32), 512, 0, stream>>>(xT, W2, out);
}

// Round 3
// 175.449 us; speedup vs baseline: 1.5260x; 1.1481x over previous
//
#include <hip/hip_runtime.h>
#include <hip/hip_bf16.h>
#include <math.h>

#define B_   32
#define CI   256
#define CO   256
#define KW   7
#define NW   8
#define SQD  8
#define L_   4096

typedef __attribute__((ext_vector_type(8))) __bf16 bf16x8;
typedef __attribute__((ext_vector_type(4))) float  f32x4;

static __device__ __forceinline__ unsigned short f2bf(float f) {
    unsigned int u = __builtin_bit_cast(unsigned int, f);
    u += 0x7FFFu + ((u >> 16) & 1u);
    return (unsigned short)(u >> 16);
}

// ---------------------------------------------------------------------------
// k1: mean over L only (deterministic, no atomics). One block per (b,i) row.
// ---------------------------------------------------------------------------
__global__ __launch_bounds__(256) void k1_mean(
        const float* __restrict__ x, float* __restrict__ pooled) {
    int row = blockIdx.x;                       // b*CI + i
    const float* p = x + (size_t)row * L_;
    int t = threadIdx.x;
    float s = 0.f;
#pragma unroll
    for (int it = 0; it < 4; ++it) {
        float4 v = *(const float4*)(p + (size_t)(t + 256 * it) * 4);
        s += v.x + v.y + v.z + v.w;
    }
    for (int m = 1; m <= 32; m <<= 1) s += __shfl_xor(s, m);
    __shared__ float wsum[4];
    if ((t & 63) == 0) wsum[t >> 6] = s;
    __syncthreads();
    if (t == 0)
        pooled[row] = (wsum[0] + wsum[1] + wsum[2] + wsum[3]) * (1.0f / L_);
}

// ---------------------------------------------------------------------------
// k2: squeeze net + gates. one block (1 wave) per sample. pooled = mean.
// ---------------------------------------------------------------------------
__global__ __launch_bounds__(64) void k2_gates(
        const float* __restrict__ pooled,
        const float* __restrict__ w1, const float* __restrict__ b1,
        const float* __restrict__ wk, const float* __restrict__ wi,
        const float* __restrict__ wo, const float* __restrict__ wn,
        float* __restrict__ kr,   // [B][8] (stride 8, 7 used)
        float* __restrict__ inc,  // [B][CI]
        float* __restrict__ outc, // [B][CO]
        float* __restrict__ nums) // [B][NW]
{
    int b = blockIdx.x, lane = threadIdx.x;
    float pc[4];
#pragma unroll
    for (int j = 0; j < 4; ++j)
        pc[j] = pooled[b * CI + lane + 64 * j];
    float h[SQD];
#pragma unroll
    for (int s = 0; s < SQD; ++s) {
        float ps = 0.f;
#pragma unroll
        for (int j = 0; j < 4; ++j)
            ps += pc[j] * w1[(lane + 64 * j) * SQD + s];
        for (int m = 1; m <= 32; m <<= 1) ps += __shfl_xor(ps, m);
        float z = ps + b1[s];
        h[s] = 0.5f * z * (1.0f + erff(z * 0.70710678118654752f));
    }
    if (lane < KW) {
        float a = 0.f;
#pragma unroll
        for (int s = 0; s < SQD; ++s) a += h[s] * wk[s * KW + lane];
        kr[b * 8 + lane] = 1.0f / (1.0f + expf(-a));
    }
    if (lane < NW) {
        float e[NW]; float mx = -1e30f;
#pragma unroll
        for (int n = 0; n < NW; ++n) {
            float a = 0.f;
#pragma unroll
            for (int s = 0; s < SQD; ++s) a += h[s] * wn[s * NW + n];
            e[n] = a; mx = fmaxf(mx, a);
        }
        float den = 0.f;
#pragma unroll
        for (int n = 0; n < NW; ++n) den += expf(e[n] - mx);
        nums[b * NW + lane] = expf(e[lane] - mx) / den;
    }
#pragma unroll
    for (int j = 0; j < 4; ++j) {
        int c = lane + 64 * j;
        float a = 0.f, o2 = 0.f;
#pragma unroll
        for (int s = 0; s < SQD; ++s) {
            a  += h[s] * wi[s * CI + c];
            o2 += h[s] * wo[s * CO + c];
        }
        inc[b * CI + c]  = 1.0f / (1.0f + expf(-a));
        outc[b * CO + c] = 1.0f / (1.0f + expf(-o2));
    }
}

// ---------------------------------------------------------------------------
// k3: per-sample mixed weights in MFMA-native layout
//     W2[b][k][i/32][o][i%32] (bf16).  256 blocks x 256 threads.
// ---------------------------------------------------------------------------
__global__ __launch_bounds__(256) void k3_wgen(
        const float* __restrict__ cw,      // [CO][CI][KW][NW]
        const float* __restrict__ kr, const float* __restrict__ inc,
        const float* __restrict__ outc, const float* __restrict__ nums,
        unsigned short* __restrict__ W2) {
    __shared__ float s_nums[B_][NW];
    __shared__ float s_kr[B_][KW];
    __shared__ float s_inc[B_][32];
    __shared__ float s_outc[B_][8];
    int t = threadIdx.x;
    int ic = blockIdx.x & 7, o0 = (blockIdx.x >> 3) * 8;
    s_nums[t >> 3][t & 7] = nums[t];
    if (t < B_ * KW) s_kr[t / KW][t % KW] = kr[(t / KW) * 8 + (t % KW)];
    for (int u = t; u < 32 * 32; u += 256) {
        int bb = u >> 5, ii = u & 31;
        s_inc[bb][ii] = inc[bb * CI + ic * 32 + ii];
    }
    for (int u = t; u < 32 * 8; u += 256) {
        int bb = u >> 3, oo = u & 7;
        s_outc[bb][oo] = outc[bb * CO + o0 + oo];
    }
    __syncthreads();
    int ii = t & 31, oo = t >> 5;
    int o = o0 + oo, i = ic * 32 + ii;
    float cwv[KW][NW];
    const float* p = cw + ((size_t)(o * CI + i)) * (KW * NW);
#pragma unroll
    for (int k = 0; k < KW; ++k)
#pragma unroll
        for (int n = 0; n < NW; ++n) cwv[k][n] = p[k * NW + n];
    for (int bb = 0; bb < B_; ++bb) {
        float gio = s_inc[bb][ii] * s_outc[bb][oo];
#pragma unroll
        for (int k = 0; k < KW; ++k) {
            float sk = 0.f;
#pragma unroll
            for (int n = 0; n < NW; ++n) sk += s_nums[bb][n] * cwv[k][n];
            float w = s_kr[bb][k] * gio * sk;
            W2[(((size_t)(bb * KW + k) * 8 + ic) * CO + o) * 32 + ii] = f2bf(w);
        }
    }
}

// ---------------------------------------------------------------------------
// k4: fused transpose + per-sample im2col GEMM (16x16x32 bf16 MFMA).
//     Block = 256 o x 128 l; 8 waves of 32o x 128l; acc[2][8].
//     LDS: xs[134][256] bf16 (67 KB) -> 2 blocks/CU, 4 waves/SIMD.
//     Staged directly from fp32 x with in-LDS transpose; 16B-unit XOR
//     swizzle: unit u of row r stored at u^(r&7).
//     Grid: 1024 blocks, XCD-bijective swizzle so each sample's 32
//     l-blocks share one XCD (W2 L2-resident).
// ---------------------------------------------------------------------------
__global__ __launch_bounds__(512, 4) void k4_conv(
        const float* __restrict__ x,             // fp32 [B][CI][L]
        const unsigned short* __restrict__ W2,   // bf16 [B][KW][8][CO][32]
        float* __restrict__ out) {               // [B][CO][L]
    __shared__ __align__(16) unsigned short xs[134 * 256];
    int bid = blockIdx.x;
    int wg  = (bid & 7) * 128 + (bid >> 3);      // XCD-bijective (1024%8==0)
    int b = wg >> 5, l0 = (wg & 31) * 128;
    int t = threadIdx.x;
    const float* xb = x + (size_t)b * CI * L_;

    // main staging: rows r=3..130 (gl = l0..l0+127), all 256 i
    {
        int c = t & 31;                          // float4 chunk (4 l's)
        int i = t >> 5;                          // 16 i's per iteration
#pragma unroll 4
        for (int it = 0; it < 16; ++it, i += 16) {
            float4 v = *(const float4*)(xb + (size_t)i * L_ + l0 + c * 4);
            int u0 = i >> 3, isub = i & 7;
#pragma unroll
            for (int j = 0; j < 4; ++j) {
                int r = c * 4 + j + 3;
                xs[r * 256 + ((u0 ^ (r & 7)) * 8) + isub] = f2bf((&v.x)[j]);
            }
        }
    }
    // halo: rows 0..2 and 131..133 (gl = l0-3..l0-1, l0+128..l0+130)
    for (int u = t; u < 6 * 256; u += 512) {
        int h = u >> 8, i = u & 255;
        int r = (h < 3) ? h : 128 + h;
        int gl = l0 - 3 + r;
        float f = (gl >= 0 && gl < L_) ? xb[(size_t)i * L_ + gl] : 0.f;
        xs[r * 256 + (((i >> 3) ^ (r & 7)) * 8) + (i & 7)] = f2bf(f);
    }
    __syncthreads();

    int lane = t & 63, wid = t >> 6;
    int o_base = wid * 32;                       // 8 waves tile o exactly
    int ml = lane & 15, kg = lane >> 4;

    f32x4 acc[2][8];
#pragma unroll
    for (int a = 0; a < 2; ++a)
#pragma unroll
        for (int c = 0; c < 8; ++c) acc[a][c] = (f32x4){0.f, 0.f, 0.f, 0.f};

    const unsigned short* wbase = W2 + (size_t)b * (KW * 8 * CO * 32);
    for (int k = 0; k < KW; ++k) {
        const unsigned short* wk_ = wbase + (size_t)k * (8 * CO * 32);
#pragma unroll
        for (int icc = 0; icc < 8; ++icc) {
            const unsigned short* wkc = wk_ + icc * (CO * 32);
            bf16x8 af[2];
#pragma unroll
            for (int mt = 0; mt < 2; ++mt)
                af[mt] = *(const bf16x8*)(wkc + (o_base + mt * 16 + ml) * 32 + kg * 8);
            bf16x8 bfr[8];
#pragma unroll
            for (int nt = 0; nt < 8; ++nt) {
                int r = nt * 16 + ml + k;
                int unit = (icc * 4 + kg) ^ (r & 7);
                bfr[nt] = *(const bf16x8*)(xs + r * 256 + unit * 8);
            }
            __builtin_amdgcn_s_setprio(1);
#pragma unroll
            for (int mt = 0; mt < 2; ++mt)
#pragma unroll
                for (int nt = 0; nt < 8; ++nt)
                    acc[mt][nt] = __builtin_amdgcn_mfma_f32_16x16x32_bf16(
                        af[mt], bfr[nt], acc[mt][nt], 0, 0, 0);
            __builtin_amdgcn_s_setprio(0);
        }
    }

    // epilogue: D row(o)=(lane>>4)*4+q, col(l)=lane&15
#pragma unroll
    for (int mt = 0; mt < 2; ++mt) {
        int o = o_base + mt * 16 + kg * 4;
#pragma unroll
        for (int nt = 0; nt < 8; ++nt) {
            int l = l0 + nt * 16 + ml;
            float* po = out + ((size_t)(b * CO + o)) * L_ + l;
#pragma unroll
            for (int q = 0; q < 4; ++q)
                po[(size_t)q * L_] = acc[mt][nt][q];
        }
    }
}

// ---------------------------------------------------------------------------
extern "C" void kernel_launch(void* const* d_in, const int* in_sizes, int n_in,
                              void* d_out, int out_size, void* d_ws, size_t ws_size,
                              hipStream_t stream) {
    const float* x  = (const float*)d_in[0];
    const float* cw = (const float*)d_in[1];
    const float* w1 = (const float*)d_in[2];
    const float* b1 = (const float*)d_in[3];
    const float* wk = (const float*)d_in[4];
    const float* wi = (const float*)d_in[5];
    const float* wo = (const float*)d_in[6];
    const float* wn = (const float*)d_in[7];
    float* out = (float*)d_out;

    char* ws = (char*)d_ws;
    const size_t off_W2     = 0;                 // 32*7*8*256*32*2 = 29360128
    const size_t off_pooled = 29360128;          // 32*256*4
    const size_t off_kr     = 29392896;          // 32*8*4
    const size_t off_inc    = 29393920;          // 32768
    const size_t off_outc   = 29426688;          // 32768
    const size_t off_nums   = 29459456;          // 1024

    unsigned short* W2 = (unsigned short*)(ws + off_W2);
    float* pooled = (float*)(ws + off_pooled);
    float* kr     = (float*)(ws + off_kr);
    float* inc    = (float*)(ws + off_inc);
    float* outc   = (float*)(ws + off_outc);
    float* nums   = (float*)(ws + off_nums);

    k1_mean<<<B_ * CI, 256, 0, stream>>>(x, pooled);
    k2_gates<<<B_, 64, 0, stream>>>(pooled, w1, b1, wk, wi, wo, wn,
                                    kr, inc, outc, nums);
    k3_wgen<<<256, 256, 0, stream>>>(cw, kr, inc, outc, nums, W2);
    k4_conv<<<1024, 512, 0, stream>>>(x, W2, out);
}

// Round 5
// 172.775 us; speedup vs baseline: 1.5496x; 1.0155x over previous
//
#include <hip/hip_runtime.h>
#include <hip/hip_bf16.h>
#include <math.h>

#define B_   32
#define CI   256
#define CO   256
#define KW   7
#define NW   8
#define SQD  8
#define L_   4096

typedef __attribute__((ext_vector_type(8))) __bf16 bf16x8;
typedef __attribute__((ext_vector_type(4))) float  f32x4;

static __device__ __forceinline__ unsigned short f2bf(float f) {
    unsigned int u = __builtin_bit_cast(unsigned int, f);
    u += 0x7FFFu + ((u >> 16) & 1u);
    return (unsigned short)(u >> 16);
}
static __device__ __forceinline__ unsigned int pack2bf(float a, float b) {
    return (unsigned int)f2bf(a) | ((unsigned int)f2bf(b) << 16);
}

// ---------------------------------------------------------------------------
// k1: mean over L (deterministic). One block per (b,i) row.
// ---------------------------------------------------------------------------
__global__ __launch_bounds__(256) void k1_mean(
        const float* __restrict__ x, float* __restrict__ pooled) {
    int row = blockIdx.x;                       // b*CI + i
    const float* p = x + (size_t)row * L_;
    int t = threadIdx.x;
    float s = 0.f;
#pragma unroll
    for (int it = 0; it < 4; ++it) {
        float4 v = *(const float4*)(p + (size_t)(t + 256 * it) * 4);
        s += v.x + v.y + v.z + v.w;
    }
    for (int m = 1; m <= 32; m <<= 1) s += __shfl_xor(s, m);
    __shared__ float wsum[4];
    if ((t & 63) == 0) wsum[t >> 6] = s;
    __syncthreads();
    if (t == 0)
        pooled[row] = (wsum[0] + wsum[1] + wsum[2] + wsum[3]) * (1.0f / L_);
}

// ---------------------------------------------------------------------------
// k2: squeeze net + gates. one block (1 wave) per sample.
// ---------------------------------------------------------------------------
__global__ __launch_bounds__(64) void k2_gates(
        const float* __restrict__ pooled,
        const float* __restrict__ w1, const float* __restrict__ b1,
        const float* __restrict__ wk, const float* __restrict__ wi,
        const float* __restrict__ wo, const float* __restrict__ wn,
        float* __restrict__ kr, float* __restrict__ inc,
        float* __restrict__ outc, float* __restrict__ nums)
{
    int b = blockIdx.x, lane = threadIdx.x;
    float pc[4];
#pragma unroll
    for (int j = 0; j < 4; ++j)
        pc[j] = pooled[b * CI + lane + 64 * j];
    float h[SQD];
#pragma unroll
    for (int s = 0; s < SQD; ++s) {
        float ps = 0.f;
#pragma unroll
        for (int j = 0; j < 4; ++j)
            ps += pc[j] * w1[(lane + 64 * j) * SQD + s];
        for (int m = 1; m <= 32; m <<= 1) ps += __shfl_xor(ps, m);
        float z = ps + b1[s];
        h[s] = 0.5f * z * (1.0f + erff(z * 0.70710678118654752f));
    }
    if (lane < KW) {
        float a = 0.f;
#pragma unroll
        for (int s = 0; s < SQD; ++s) a += h[s] * wk[s * KW + lane];
        kr[b * 8 + lane] = 1.0f / (1.0f + expf(-a));
    }
    if (lane < NW) {
        float e[NW]; float mx = -1e30f;
#pragma unroll
        for (int n = 0; n < NW; ++n) {
            float a = 0.f;
#pragma unroll
            for (int s = 0; s < SQD; ++s) a += h[s] * wn[s * NW + n];
            e[n] = a; mx = fmaxf(mx, a);
        }
        float den = 0.f;
#pragma unroll
        for (int n = 0; n < NW; ++n) den += expf(e[n] - mx);
        nums[b * NW + lane] = expf(e[lane] - mx) / den;
    }
#pragma unroll
    for (int j = 0; j < 4; ++j) {
        int c = lane + 64 * j;
        float a = 0.f, o2 = 0.f;
#pragma unroll
        for (int s = 0; s < SQD; ++s) {
            a  += h[s] * wi[s * CI + c];
            o2 += h[s] * wo[s * CO + c];
        }
        inc[b * CI + c]  = 1.0f / (1.0f + expf(-a));
        outc[b * CO + c] = 1.0f / (1.0f + expf(-o2));
    }
}

// ---------------------------------------------------------------------------
// k3: per-sample mixed weights, MFMA layout W2[b][k*8+ic][o][i%32] bf16.
// ---------------------------------------------------------------------------
__global__ __launch_bounds__(256) void k3_wgen(
        const float* __restrict__ cw,
        const float* __restrict__ kr, const float* __restrict__ inc,
        const float* __restrict__ outc, const float* __restrict__ nums,
        unsigned short* __restrict__ W2) {
    __shared__ float s_nums[B_][NW];
    __shared__ float s_kr[B_][KW];
    __shared__ float s_inc[B_][32];
    __shared__ float s_outc[B_][8];
    int t = threadIdx.x;
    int ic = blockIdx.x & 7, o0 = (blockIdx.x >> 3) * 8;
    s_nums[t >> 3][t & 7] = nums[t];
    if (t < B_ * KW) s_kr[t / KW][t % KW] = kr[(t / KW) * 8 + (t % KW)];
    for (int u = t; u < 32 * 32; u += 256) {
        int bb = u >> 5, ii = u & 31;
        s_inc[bb][ii] = inc[bb * CI + ic * 32 + ii];
    }
    for (int u = t; u < 32 * 8; u += 256) {
        int bb = u >> 3, oo = u & 7;
        s_outc[bb][oo] = outc[bb * CO + o0 + oo];
    }
    __syncthreads();
    int ii = t & 31, oo = t >> 5;
    int o = o0 + oo, i = ic * 32 + ii;
    float cwv[KW][NW];
    const float* p = cw + ((size_t)(o * CI + i)) * (KW * NW);
#pragma unroll
    for (int k = 0; k < KW; ++k)
#pragma unroll
        for (int n = 0; n < NW; ++n) cwv[k][n] = p[k * NW + n];
    for (int bb = 0; bb < B_; ++bb) {
        float gio = s_inc[bb][ii] * s_outc[bb][oo];
#pragma unroll
        for (int k = 0; k < KW; ++k) {
            float sk = 0.f;
#pragma unroll
            for (int n = 0; n < NW; ++n) sk += s_nums[bb][n] * cwv[k][n];
            float w = s_kr[bb][k] * gio * sk;
            W2[(((size_t)(bb * KW + k) * 8 + ic) * CO + o) * 32 + ii] = f2bf(w);
        }
    }
}

// ---------------------------------------------------------------------------
// k4: fused transpose + per-sample im2col GEMM (16x16x32 bf16 MFMA).
//     Block = 256 o x 256 l; 8 waves (4o x 2l), wave = 64o x 128l, acc[4][8].
//     LDS xs[262][256] bf16 (134 KB), swizzle sw(r)=(r&7)^((r>>2)&7) on 16B
//     units: ds_read_b128 balanced, ds_write_b64 staging 4-way max.
//     K-loop: 56 steps, manual 2-deep register pipeline.
// ---------------------------------------------------------------------------
__global__ __launch_bounds__(512, 2) void k4_conv(
        const float* __restrict__ x,             // fp32 [B][CI][L]
        const unsigned short* __restrict__ W2,   // bf16 [B][56][CO][32]
        float* __restrict__ out) {               // [B][CO][L]
    __shared__ __align__(16) unsigned short xs[262 * 256];
    int bid = blockIdx.x;
    int wg  = (bid & 7) * 64 + (bid >> 3);       // XCD-bijective (512%8==0)
    int b = wg >> 4, l0 = (wg & 15) * 256;
    int t = threadIdx.x;
    const float* xb = x + (size_t)b * CI * L_;

    // ---- main staging: rows 3..258 (l = l0..l0+255), all 256 i ----
    {
        int ch = (t & 31) + 32 * (t >> 8);       // l-chunk 0..63
        int g  = (t >> 5) & 7;                   // i-group
#pragma unroll
        for (int it = 0; it < 8; ++it) {
            int i0 = g * 4 + it * 32;
            float4 f0 = *(const float4*)(xb + (size_t)(i0 + 0) * L_ + l0 + ch * 4);
            float4 f1 = *(const float4*)(xb + (size_t)(i0 + 1) * L_ + l0 + ch * 4);
            float4 f2 = *(const float4*)(xb + (size_t)(i0 + 2) * L_ + l0 + ch * 4);
            float4 f3 = *(const float4*)(xb + (size_t)(i0 + 3) * L_ + l0 + ch * 4);
            int u = i0 >> 3, h = (i0 >> 2) & 1;
#pragma unroll
            for (int j = 0; j < 4; ++j) {
                int r = 4 * ch + j + 3;
                uint2 w;
                w.x = pack2bf((&f0.x)[j], (&f1.x)[j]);
                w.y = pack2bf((&f2.x)[j], (&f3.x)[j]);
                int sw = (r & 7) ^ ((r >> 2) & 7);
                *(uint2*)(xs + r * 256 + ((u ^ sw) * 8) + h * 4) = w;
            }
        }
    }
    // ---- halo: rows 0..2 (l0-3..l0-1) and 259..261 (l0+256..l0+258) ----
    if (t < 128) {
        bool left = t < 64;
        int tt = left ? t : t - 64;
        int i0 = tt * 4;
        int gl4 = left ? l0 - 4 : l0 + 256;
        bool ok = left ? (l0 > 0) : (l0 + 256 < L_);
        float4 f[4];
#pragma unroll
        for (int d = 0; d < 4; ++d)
            f[d] = ok ? *(const float4*)(xb + (size_t)(i0 + d) * L_ + gl4)
                      : make_float4(0.f, 0.f, 0.f, 0.f);
        int u = i0 >> 3, h = (i0 >> 2) & 1;
#pragma unroll
        for (int j = 0; j < 4; ++j) {
            if (left && j == 0) continue;
            if (!left && j == 3) continue;
            int r = left ? (j - 1) : (259 + j);
            uint2 w;
            w.x = pack2bf((&f[0].x)[j], (&f[1].x)[j]);
            w.y = pack2bf((&f[2].x)[j], (&f[3].x)[j]);
            int sw = (r & 7) ^ ((r >> 2) & 7);
            *(uint2*)(xs + r * 256 + ((u ^ sw) * 8) + h * 4) = w;
        }
    }
    __syncthreads();

    int lane = t & 63, wid = t >> 6;
    int o_base = (wid & 3) * 64;
    int l_off  = (wid >> 2) * 128;
    int ml = lane & 15, kg = lane >> 4;

    f32x4 acc[4][8];
#pragma unroll
    for (int a = 0; a < 4; ++a)
#pragma unroll
        for (int c = 0; c < 8; ++c) acc[a][c] = (f32x4){0.f, 0.f, 0.f, 0.f};

    const unsigned short* wbase = W2 + (size_t)b * (56 * CO * 32);

    auto LOADF = [&](bf16x8 (&AF)[4], bf16x8 (&BF)[8], int S) {
        int k_ = S >> 3, icc_ = S & 7;
        const unsigned short* wkc = wbase + (size_t)S * (CO * 32);
#pragma unroll
        for (int mt = 0; mt < 4; ++mt)
            AF[mt] = *(const bf16x8*)(wkc + (o_base + mt * 16 + ml) * 32 + kg * 8);
#pragma unroll
        for (int nt = 0; nt < 8; ++nt) {
            int r = l_off + nt * 16 + ml + k_;
            int unit = (icc_ * 4 + kg) ^ ((r & 7) ^ ((r >> 2) & 7));
            BF[nt] = *(const bf16x8*)(xs + r * 256 + unit * 8);
        }
    };
    auto DOMFMA = [&](bf16x8 (&AF)[4], bf16x8 (&BF)[8]) {
        __builtin_amdgcn_s_setprio(1);
#pragma unroll
        for (int mt = 0; mt < 4; ++mt)
#pragma unroll
            for (int nt = 0; nt < 8; ++nt)
                acc[mt][nt] = __builtin_amdgcn_mfma_f32_16x16x32_bf16(
                    AF[mt], BF[nt], acc[mt][nt], 0, 0, 0);
        __builtin_amdgcn_s_setprio(0);
    };

    bf16x8 afA[4], bfA[8], afB[4], bfB[8];
    LOADF(afA, bfA, 0);
    for (int s = 0; s < 56; s += 2) {
        LOADF(afB, bfB, s + 1);
        DOMFMA(afA, bfA);
        if (s + 2 < 56) LOADF(afA, bfA, s + 2);
        DOMFMA(afB, bfB);
    }

    // epilogue: D row(o)=(lane>>4)*4+q, col(l)=lane&15
#pragma unroll
    for (int mt = 0; mt < 4; ++mt) {
        int o = o_base + mt * 16 + kg * 4;
#pragma unroll
        for (int nt = 0; nt < 8; ++nt) {
            int l = l0 + l_off + nt * 16 + ml;
            float* po = out + ((size_t)(b * CO + o)) * L_ + l;
#pragma unroll
            for (int q = 0; q < 4; ++q)
                po[(size_t)q * L_] = acc[mt][nt][q];
        }
    }
}

// ---------------------------------------------------------------------------
extern "C" void kernel_launch(void* const* d_in, const int* in_sizes, int n_in,
                              void* d_out, int out_size, void* d_ws, size_t ws_size,
                              hipStream_t stream) {
    const float* x  = (const float*)d_in[0];
    const float* cw = (const float*)d_in[1];
    const float* w1 = (const float*)d_in[2];
    const float* b1 = (const float*)d_in[3];
    const float* wk = (const float*)d_in[4];
    const float* wi = (const float*)d_in[5];
    const float* wo = (const float*)d_in[6];
    const float* wn = (const float*)d_in[7];
    float* out = (float*)d_out;

    char* ws = (char*)d_ws;
    unsigned short* W2 = (unsigned short*)(ws + 0);          // 29360128 B
    float* pooled = (float*)(ws + 29360128);
    float* kr     = (float*)(ws + 29392896);
    float* inc    = (float*)(ws + 29393920);
    float* outc   = (float*)(ws + 29426688);
    float* nums   = (float*)(ws + 29459456);

    k1_mean<<<B_ * CI, 256, 0, stream>>>(x, pooled);
    k2_gates<<<B_, 64, 0, stream>>>(pooled, w1, b1, wk, wi, wo, wn,
                                    kr, inc, outc, nums);
    k3_wgen<<<256, 256, 0, stream>>>(cw, kr, inc, outc, nums, W2);
    k4_conv<<<512, 512, 0, stream>>>(x, W2, out);
}